// Round 5
// baseline (508.483 us; speedup 1.0000x reference)
//
#include <hip/hip_runtime.h>
#include <math.h>

#define NND 200000
#define NEV 100000
#define MD 100
#define TD 100
#define MSGD 172
#define NB 64
#define TILE_BYTES 61440  // 64 rows * 480 cols * 2B

typedef __attribute__((ext_vector_type(8))) short bf16x8;
typedef __attribute__((ext_vector_type(4))) float f32x4;

__device__ __forceinline__ float sigmoidf_(float x) { return 1.0f / (1.0f + expf(-x)); }

__device__ __forceinline__ unsigned short f2bf(float f) {
    union { float f; unsigned int u; } v; v.f = f;
    unsigned int r = (v.u + 0x7FFFu + ((v.u >> 16) & 1u)) >> 16;
    return (unsigned short)r;
}
__device__ __forceinline__ float bf2f(unsigned short h) {
    union { unsigned int u; float f; } v; v.u = ((unsigned int)h) << 16;
    return v.f;
}

__device__ __forceinline__ void gload_lds16(const void* g, void* l) {
    __builtin_amdgcn_global_load_lds(
        (const __attribute__((address_space(1))) unsigned int*)g,
        (__attribute__((address_space(3))) unsigned int*)l, 16, 0, 0);
}

// ---------------- K2: count events per node ----------------
__global__ __launch_bounds__(256) void k_count(
    const int* __restrict__ src, const int* __restrict__ dst, int* __restrict__ cnt)
{
    int e = blockIdx.x * 256 + threadIdx.x;
    if (e >= NEV) return;
    atomicAdd(&cnt[src[e]], 1);
    atomicAdd(&cnt[dst[e]], 1);
}

// ---------------- K3a: per-1024-block exclusive scan ----------------
__global__ __launch_bounds__(256) void k_scan1(
    const int* __restrict__ cnt, int* __restrict__ off, int* __restrict__ psum)
{
    __shared__ int sdat[256];
    int t = threadIdx.x, b = blockIdx.x;
    int i0 = b * 1024 + t * 4;
    int v0 = (i0 + 0 < NND) ? cnt[i0 + 0] : 0;
    int v1 = (i0 + 1 < NND) ? cnt[i0 + 1] : 0;
    int v2 = (i0 + 2 < NND) ? cnt[i0 + 2] : 0;
    int v3 = (i0 + 3 < NND) ? cnt[i0 + 3] : 0;
    int tsum = v0 + v1 + v2 + v3;
    sdat[t] = tsum;
    __syncthreads();
    for (int o = 1; o < 256; o <<= 1) {
        int x = (t >= o) ? sdat[t - o] : 0;
        __syncthreads();
        sdat[t] += x;
        __syncthreads();
    }
    int excl = sdat[t] - tsum;
    if (i0 + 0 < NND) off[i0 + 0] = excl;
    if (i0 + 1 < NND) off[i0 + 1] = excl + v0;
    if (i0 + 2 < NND) off[i0 + 2] = excl + v0 + v1;
    if (i0 + 3 < NND) off[i0 + 3] = excl + v0 + v1 + v2;
    if (t == 255) psum[b] = sdat[255];
}

// ---------------- K3b: scan block sums ----------------
__global__ __launch_bounds__(256) void k_scan2(int* __restrict__ psum, int nblk)
{
    __shared__ int sdat[256];
    int t = threadIdx.x;
    int v = (t < nblk) ? psum[t] : 0;
    sdat[t] = v;
    __syncthreads();
    for (int o = 1; o < 256; o <<= 1) {
        int x = (t >= o) ? sdat[t - o] : 0;
        __syncthreads();
        sdat[t] += x;
        __syncthreads();
    }
    if (t < nblk) psum[t] = sdat[t] - v;  // exclusive
}

// ---------------- K3c: add block offsets; init cursor ----------------
__global__ __launch_bounds__(256) void k_scan3(
    int* __restrict__ off, const int* __restrict__ psum, int* __restrict__ cur)
{
    int t = threadIdx.x, b = blockIdx.x;
    int base = psum[b];
    int i0 = b * 1024 + t * 4;
#pragma unroll
    for (int j = 0; j < 4; ++j) {
        int i = i0 + j;
        if (i < NND) {
            int v = off[i] + base;
            off[i] = v;
            cur[i] = v;
        }
    }
}

// ---------------- K4: place entries (other, eid, trel) ----------------
__global__ __launch_bounds__(256) void k_place(
    const int* __restrict__ src, const int* __restrict__ dst,
    const int* __restrict__ tarr, const int* __restrict__ last_update,
    int* __restrict__ cur, int4* __restrict__ entries)
{
    int e = blockIdx.x * 256 + threadIdx.x;
    if (e >= NEV) return;
    int s = src[e], d = dst[e], tt = tarr[e];
    int slot = atomicAdd(&cur[s], 1);
    entries[slot] = make_int4(d, e, __float_as_int((float)(tt - last_update[s])), 0);
    slot = atomicAdd(&cur[d], 1);
    entries[slot] = make_int4(s, e, __float_as_int((float)(tt - last_update[d])), 0);
}

// ---------------- weight prep: bf16 in MFMA B-fragment order ----------------
#define WP_SH (15 * 4 * 5 * 64 * 8)
#define UP_SH (4 * 4 * 5 * 64 * 8)
__global__ __launch_bounds__(256) void tgn_prep(
    const float* __restrict__ w_ih, const float* __restrict__ w_hh,
    unsigned short* __restrict__ Wp, unsigned short* __restrict__ Up)
{
    int idx = blockIdx.x * 256 + threadIdx.x;
    if (idx < WP_SH) {
        int e = idx & 7;
        int lane = (idx >> 3) & 63;
        int t = idx >> 9;
        int f = t % 5;
        int t2 = t / 5;
        int nw = t2 & 3;
        int ks = t2 >> 2;
        int col = nw * 80 + f * 16 + (lane & 15);
        int k = ks * 32 + ((lane >> 4) << 3) + e;
        float v = (col < 300 && k < 472) ? w_ih[col * 472 + k] : 0.0f;
        Wp[idx] = f2bf(v);
    } else {
        int j = idx - WP_SH;
        if (j < UP_SH) {
            int e = j & 7;
            int lane = (j >> 3) & 63;
            int t = j >> 9;
            int f = t % 5;
            int t2 = t / 5;
            int nw = t2 & 3;
            int ks = t2 >> 2;
            int col = nw * 80 + f * 16 + (lane & 15);
            int k = ks * 32 + ((lane >> 4) << 3) + e;
            float v = (col < 300 && k < 100) ? w_hh[col * 100 + k] : 0.0f;
            Up[j] = f2bf(v);
        }
    }
}

// ---------------- K_aggr: build bf16 A-matrix rows, pre-swizzled ----------------
// Row layout (k): [0,100)=memory[self] | [100,200)=mean mem_other | [200,372)=mean raw_msg
//                 | [372,472)=mean cos-enc | [472,480)=0.  Written at byte
//                 tile(n>>6) + ((n&63)*960 + 8u) ^ ((n&7)<<4)  for 8-byte unit u.
__global__ __launch_bounds__(256) void k_aggr(
    const float* __restrict__ memory, const float* __restrict__ raw_msg,
    const float* __restrict__ time_w, const float* __restrict__ time_b,
    const int* __restrict__ cnt, const int* __restrict__ off,
    const int4* __restrict__ entries, unsigned short* __restrict__ agg)
{
    int tid = threadIdx.x;
    int node = blockIdx.x * 32 + (tid >> 3);
    int tsub = tid & 7;
    if (node >= NND) return;
    int c = cnt[node];
    int o0 = off[node];

    const float4* tw4 = reinterpret_cast<const float4*>(time_w);
    const float4* tb4 = reinterpret_cast<const float4*>(time_b);

    // acc[j] covers 8-byte unit u = tsub + 8j (4 floats each); gather region 25<=u<118
    float4 acc[15];
#pragma unroll
    for (int j = 0; j < 15; ++j) acc[j] = (float4){0.f, 0.f, 0.f, 0.f};

    for (int i = 0; i < c; ++i) {
        int4 en = entries[o0 + i];
        const float4* mo = reinterpret_cast<const float4*>(memory + (size_t)en.x * MD);
        const float4* rw = reinterpret_cast<const float4*>(raw_msg + (size_t)en.y * MSGD);
        float trel = __int_as_float(en.z);
#pragma unroll
        for (int j = 0; j < 15; ++j) {
            int u = tsub + 8 * j;
            if (u >= 25 && u < 118) {
                int q = u - 25;
                float4 v;
                if (q < 25) {
                    v = mo[q];
                } else if (q < 68) {
                    v = rw[q - 25];
                } else {
                    float4 w = tw4[q - 68], b = tb4[q - 68];
                    v.x = cosf(trel * w.x + b.x);
                    v.y = cosf(trel * w.y + b.y);
                    v.z = cosf(trel * w.z + b.z);
                    v.w = cosf(trel * w.w + b.w);
                }
                acc[j].x += v.x; acc[j].y += v.y; acc[j].z += v.z; acc[j].w += v.w;
            }
        }
    }

    float ci = 1.0f / fmaxf((float)c, 1.0f);
    char* tile = reinterpret_cast<char*>(agg) + (size_t)(node >> 6) * TILE_BYTES;
    int local = node & 63;
    int rbase = local * 960;
    int swz = (local & 7) << 4;
    const float4* ms = reinterpret_cast<const float4*>(memory + (size_t)node * MD);

#pragma unroll
    for (int j = 0; j < 15; ++j) {
        int u = tsub + 8 * j;
        float4 v;
        if (u < 25) {
            v = ms[u];                       // mem_self (mean telescopes to memory[n])
        } else if (u < 118) {
            v = acc[j];
            v.x *= ci; v.y *= ci; v.z *= ci; v.w *= ci;
        } else {
            v = (float4){0.f, 0.f, 0.f, 0.f};  // pad
        }
        ushort4 h;
        h.x = f2bf(v.x); h.y = f2bf(v.y); h.z = f2bf(v.z); h.w = f2bf(v.w);
        *reinterpret_cast<ushort4*>(tile + ((rbase + 8 * u) ^ swz)) = h;
    }
}

// ---------------- K_gemm: DMA-staged bf16 MFMA GRU ----------------
__global__ __launch_bounds__(512) void tgn_gemm(
    const float* __restrict__ memory, const unsigned short* __restrict__ agg,
    const unsigned short* __restrict__ Wp, const unsigned short* __restrict__ Up,
    const float* __restrict__ b_ih, const float* __restrict__ b_hh,
    const int* __restrict__ cnt, float* __restrict__ out)
{
    __shared__ __align__(16) unsigned short lds[64 * 480];
    __shared__ float cnt_s[NB];
    int tid = threadIdx.x;
    int n0 = blockIdx.x * NB;

    if (tid < NB) cnt_s[tid] = (float)cnt[n0 + tid];

    // stage tile: 60 KB linear DMA (layout already swizzled in global)
    {
        int lane = tid & 63;
        int wv0 = tid >> 6;
        const char* gsrc = reinterpret_cast<const char*>(agg) + (size_t)blockIdx.x * TILE_BYTES;
        char* lbase = reinterpret_cast<char*>(lds);
        for (int i = wv0; i < 60; i += 8) {
            gload_lds16(gsrc + i * 1024 + lane * 16, lbase + i * 1024);
        }
    }
    __syncthreads();

    // wave layout: 2 M-groups x 4 N-groups; wave = 2 row-frags x 5 col-frags
    int lane = tid & 63;
    int wv = tid >> 6;
    int nw = wv & 3;
    int mw = wv >> 2;
    int l15 = lane & 15;
    int kg = (lane >> 4) << 3;

    f32x4 accA[2][5], accH[2][5];
#pragma unroll
    for (int g = 0; g < 2; ++g)
#pragma unroll
        for (int f = 0; f < 5; ++f) {
            accA[g][f] = (f32x4){0.f, 0.f, 0.f, 0.f};
            accH[g][f] = (f32x4){0.f, 0.f, 0.f, 0.f};
        }

    int arow0 = mw * 32 + l15;
    const bf16x8* WpB = reinterpret_cast<const bf16x8*>(Wp);
    const bf16x8* UpB = reinterpret_cast<const bf16x8*>(Up);

    for (int ks = 0; ks < 15; ++ks) {
        int k0 = ks * 32;
        bf16x8 a0, a1;
        {
            int r0 = arow0, r1 = arow0 + 16;
            int ab0 = (r0 * 960 + 2 * (k0 + kg)) ^ ((r0 & 7) << 4);
            int ab1 = (r1 * 960 + 2 * (k0 + kg)) ^ ((r1 & 7) << 4);
            a0 = *reinterpret_cast<const bf16x8*>(reinterpret_cast<const char*>(lds) + ab0);
            a1 = *reinterpret_cast<const bf16x8*>(reinterpret_cast<const char*>(lds) + ab1);
        }
        const bf16x8* wp = WpB + ((size_t)(ks * 4 + nw) * 5) * 64 + lane;
#pragma unroll
        for (int f = 0; f < 5; ++f) {
            bf16x8 b = wp[f * 64];
            accA[0][f] = __builtin_amdgcn_mfma_f32_16x16x32_bf16(a0, b, accA[0][f], 0, 0, 0);
            accA[1][f] = __builtin_amdgcn_mfma_f32_16x16x32_bf16(a1, b, accA[1][f], 0, 0, 0);
        }
    }
    for (int ks = 0; ks < 4; ++ks) {
        int k0 = ks * 32;
        bf16x8 a0, a1;
        {
            int r0 = arow0, r1 = arow0 + 16;
            int ab0 = (r0 * 960 + 2 * (k0 + kg)) ^ ((r0 & 7) << 4);
            int ab1 = (r1 * 960 + 2 * (k0 + kg)) ^ ((r1 & 7) << 4);
            a0 = *reinterpret_cast<const bf16x8*>(reinterpret_cast<const char*>(lds) + ab0);
            a1 = *reinterpret_cast<const bf16x8*>(reinterpret_cast<const char*>(lds) + ab1);
        }
        const bf16x8* up = UpB + ((size_t)(ks * 4 + nw) * 5) * 64 + lane;
#pragma unroll
        for (int f = 0; f < 5; ++f) {
            bf16x8 b = up[f * 64];
            accH[0][f] = __builtin_amdgcn_mfma_f32_16x16x32_bf16(a0, b, accH[0][f], 0, 0, 0);
            accH[1][f] = __builtin_amdgcn_mfma_f32_16x16x32_bf16(a1, b, accH[1][f], 0, 0, 0);
        }
    }

    __syncthreads();  // reuse LDS for gate staging

    unsigned short* gsum = lds;
    unsigned short* gin = lds + 64 * 208;
    unsigned short* ghn = gin + 64 * 104;

#pragma unroll
    for (int f = 0; f < 5; ++f) {
        int col = nw * 80 + f * 16 + l15;
        if (col < 300) {
            float bi = b_ih[col], bh = b_hh[col];
#pragma unroll
            for (int g = 0; g < 2; ++g) {
                int node0 = mw * 32 + g * 16 + ((lane >> 4) << 2);
#pragma unroll
                for (int r = 0; r < 4; ++r) {
                    int node = node0 + r;
                    float gi = accA[g][f][r] + bi;
                    float gh = accH[g][f][r] + bh;
                    if (col < 200) {
                        gsum[node * 208 + col] = f2bf(gi + gh);
                    } else {
                        gin[node * 104 + (col - 200)] = f2bf(gi);
                        ghn[node * 104 + (col - 200)] = f2bf(gh);
                    }
                }
            }
        }
    }
    __syncthreads();

    for (int idx = tid; idx < NB * MD; idx += 512) {
        int n = idx / MD, j = idx - n * MD;
        float rp = bf2f(gsum[n * 208 + j]);
        float zp = bf2f(gsum[n * 208 + 100 + j]);
        float inv = bf2f(gin[n * 104 + j]);
        float hnv = bf2f(ghn[n * 104 + j]);
        float r = sigmoidf_(rp);
        float z = sigmoidf_(zp);
        float nn = tanhf(inv + r * hnv);
        float mv = memory[(size_t)(n0 + n) * MD + j];
        float h = (1.0f - z) * nn + z * mv;
        out[(size_t)(n0 + n) * MD + j] = (cnt_s[n] > 0.0f) ? h : mv;
    }
}

extern "C" void kernel_launch(void* const* d_in, const int* in_sizes, int n_in,
                              void* d_out, int out_size, void* d_ws, size_t ws_size,
                              hipStream_t stream)
{
    const float* memory      = (const float*)d_in[0];
    const float* raw_msg     = (const float*)d_in[1];
    const float* time_w      = (const float*)d_in[2];
    const float* time_b      = (const float*)d_in[3];
    const float* w_ih        = (const float*)d_in[4];
    const float* w_hh        = (const float*)d_in[5];
    const float* b_ih        = (const float*)d_in[6];
    const float* b_hh        = (const float*)d_in[7];
    const int*   last_update = (const int*)d_in[8];
    const int*   src         = (const int*)d_in[9];
    const int*   dst         = (const int*)d_in[10];
    const int*   tarr        = (const int*)d_in[11];
    float* out = (float*)d_out;

    // ws layout: cnt[N] off[N] cur[N] psum[256] | entries int4[2E] | agg bf16 | Wp | Up
    int* cnt  = (int*)d_ws;
    int* off  = cnt + NND;
    int* cur  = off + NND;
    int* psum = cur + NND;
    int4* entries = (int4*)(psum + 256);
    unsigned short* agg = (unsigned short*)(entries + 2 * NEV);
    const int NTILE = NND / NB;  // 3125
    unsigned short* Wp = agg + (size_t)NTILE * (TILE_BYTES / 2);
    unsigned short* Up = Wp + WP_SH;
    size_t need = (size_t)((char*)(Up + UP_SH) - (char*)d_ws);
    if (ws_size < need) return;

    const int NBLK = (NND + 1023) / 1024;  // 196

    hipMemsetAsync(cnt, 0, NND * sizeof(int), stream);
    tgn_prep<<<(WP_SH + UP_SH + 255) / 256, 256, 0, stream>>>(w_ih, w_hh, Wp, Up);
    k_count<<<(NEV + 255) / 256, 256, 0, stream>>>(src, dst, cnt);
    k_scan1<<<NBLK, 256, 0, stream>>>(cnt, off, psum);
    k_scan2<<<1, 256, 0, stream>>>(psum, NBLK);
    k_scan3<<<NBLK, 256, 0, stream>>>(off, psum, cur);
    k_place<<<(NEV + 255) / 256, 256, 0, stream>>>(src, dst, tarr, last_update, cur, entries);
    k_aggr<<<(NND + 31) / 32, 256, 0, stream>>>(memory, raw_msg, time_w, time_b,
                                                cnt, off, entries, agg);
    tgn_gemm<<<NTILE, 512, 0, stream>>>(memory, agg, Wp, Up, b_ih, b_hh, cnt, out);
}

// Round 6
// 391.963 us; speedup vs baseline: 1.2973x; 1.2973x over previous
//
#include <hip/hip_runtime.h>
#include <math.h>

#define NND 200000
#define NEV 100000
#define MD 100
#define TD 100
#define MSGD 172
#define NB 64
#define TILE_BYTES 61440  // 64 rows * 480 cols * 2B
#define NFRAG 25          // 400 output cols (200 rz-combined | 100 i_n | 100 h_n)
#define KS 15             // K = 480
#define BP_ELEMS (KS * NFRAG * 64 * 8)
#define GLS 72            // Gl node stride (64 + 8 pad)

typedef __attribute__((ext_vector_type(8))) short bf16x8;
typedef __attribute__((ext_vector_type(4))) float f32x4;

__device__ __forceinline__ float sigmoidf_(float x) { return 1.0f / (1.0f + expf(-x)); }

__device__ __forceinline__ unsigned short f2bf(float f) {
    union { float f; unsigned int u; } v; v.f = f;
    unsigned int r = (v.u + 0x7FFFu + ((v.u >> 16) & 1u)) >> 16;
    return (unsigned short)r;
}
__device__ __forceinline__ float bf2f(unsigned short h) {
    union { unsigned int u; float f; } v; v.u = ((unsigned int)h) << 16;
    return v.f;
}

__device__ __forceinline__ void gload_lds16(const void* g, void* l) {
    __builtin_amdgcn_global_load_lds(
        (const __attribute__((address_space(1))) unsigned int*)g,
        (__attribute__((address_space(3))) unsigned int*)l, 16, 0, 0);
}

// ---------------- K2: count events per node ----------------
__global__ __launch_bounds__(256) void k_count(
    const int* __restrict__ src, const int* __restrict__ dst, int* __restrict__ cnt)
{
    int e = blockIdx.x * 256 + threadIdx.x;
    if (e >= NEV) return;
    atomicAdd(&cnt[src[e]], 1);
    atomicAdd(&cnt[dst[e]], 1);
}

// ---------------- K3a: per-1024-block exclusive scan ----------------
__global__ __launch_bounds__(256) void k_scan1(
    const int* __restrict__ cnt, int* __restrict__ off, int* __restrict__ psum)
{
    __shared__ int sdat[256];
    int t = threadIdx.x, b = blockIdx.x;
    int i0 = b * 1024 + t * 4;
    int v0 = (i0 + 0 < NND) ? cnt[i0 + 0] : 0;
    int v1 = (i0 + 1 < NND) ? cnt[i0 + 1] : 0;
    int v2 = (i0 + 2 < NND) ? cnt[i0 + 2] : 0;
    int v3 = (i0 + 3 < NND) ? cnt[i0 + 3] : 0;
    int tsum = v0 + v1 + v2 + v3;
    sdat[t] = tsum;
    __syncthreads();
    for (int o = 1; o < 256; o <<= 1) {
        int x = (t >= o) ? sdat[t - o] : 0;
        __syncthreads();
        sdat[t] += x;
        __syncthreads();
    }
    int excl = sdat[t] - tsum;
    if (i0 + 0 < NND) off[i0 + 0] = excl;
    if (i0 + 1 < NND) off[i0 + 1] = excl + v0;
    if (i0 + 2 < NND) off[i0 + 2] = excl + v0 + v1;
    if (i0 + 3 < NND) off[i0 + 3] = excl + v0 + v1 + v2;
    if (t == 255) psum[b] = sdat[255];
}

// ---------------- K3b: scan block sums ----------------
__global__ __launch_bounds__(256) void k_scan2(int* __restrict__ psum, int nblk)
{
    __shared__ int sdat[256];
    int t = threadIdx.x;
    int v = (t < nblk) ? psum[t] : 0;
    sdat[t] = v;
    __syncthreads();
    for (int o = 1; o < 256; o <<= 1) {
        int x = (t >= o) ? sdat[t - o] : 0;
        __syncthreads();
        sdat[t] += x;
        __syncthreads();
    }
    if (t < nblk) psum[t] = sdat[t] - v;  // exclusive
}

// ---------------- K3c: add block offsets; init cursor ----------------
__global__ __launch_bounds__(256) void k_scan3(
    int* __restrict__ off, const int* __restrict__ psum, int* __restrict__ cur)
{
    int t = threadIdx.x, b = blockIdx.x;
    int base = psum[b];
    int i0 = b * 1024 + t * 4;
#pragma unroll
    for (int j = 0; j < 4; ++j) {
        int i = i0 + j;
        if (i < NND) {
            int v = off[i] + base;
            off[i] = v;
            cur[i] = v;
        }
    }
}

// ---------------- K4: place entries (other, eid, trel) ----------------
__global__ __launch_bounds__(256) void k_place(
    const int* __restrict__ src, const int* __restrict__ dst,
    const int* __restrict__ tarr, const int* __restrict__ last_update,
    int* __restrict__ cur, int4* __restrict__ entries)
{
    int e = blockIdx.x * 256 + threadIdx.x;
    if (e >= NEV) return;
    int s = src[e], d = dst[e], tt = tarr[e];
    int slot = atomicAdd(&cur[s], 1);
    entries[slot] = make_int4(d, e, __float_as_int((float)(tt - last_update[s])), 0);
    slot = atomicAdd(&cur[d], 1);
    entries[slot] = make_int4(s, e, __float_as_int((float)(tt - last_update[d])), 0);
}

// ---------------- weight prep: combined W~ in MFMA B-fragment order ----------------
// W~[col][k], col in [0,400): [0,200)=w_ih+w_hh (rz), [200,300)=w_ih (i_n),
//                             [300,400)=w_hh zero-padded (h_n).  K padded to 480.
// Bp[((ks*25+nf)*64+lane)*8+e]: col=nf*16+(lane&15), k=ks*32+((lane>>4)<<3)+e
__global__ __launch_bounds__(256) void tgn_prep(
    const float* __restrict__ w_ih, const float* __restrict__ w_hh,
    unsigned short* __restrict__ Bp)
{
    int idx = blockIdx.x * 256 + threadIdx.x;
    if (idx >= BP_ELEMS) return;
    int e = idx & 7;
    int lane = (idx >> 3) & 63;
    int t = idx >> 9;          // frag id = ks*25 + nf
    int nf = t % 25;
    int ks = t / 25;
    int col = nf * 16 + (lane & 15);
    int k = ks * 32 + ((lane >> 4) << 3) + e;
    float v = 0.0f;
    if (col < 200) {
        if (k < 472) v = w_ih[col * 472 + k];
        if (k < 100) v += w_hh[col * 100 + k];
    } else if (col < 300) {
        if (k < 472) v = w_ih[col * 472 + k];
    } else {
        if (k < 100) v = w_hh[(col - 100) * 100 + k];
    }
    Bp[idx] = f2bf(v);
}

// ---------------- K_aggr: build bf16 A-matrix rows, pre-swizzled ----------------
__global__ __launch_bounds__(256) void k_aggr(
    const float* __restrict__ memory, const float* __restrict__ raw_msg,
    const float* __restrict__ time_w, const float* __restrict__ time_b,
    const int* __restrict__ cnt, const int* __restrict__ off,
    const int4* __restrict__ entries, unsigned short* __restrict__ agg)
{
    int tid = threadIdx.x;
    int node = blockIdx.x * 32 + (tid >> 3);
    int tsub = tid & 7;
    if (node >= NND) return;
    int c = cnt[node];
    int o0 = off[node];

    const float4* tw4 = reinterpret_cast<const float4*>(time_w);
    const float4* tb4 = reinterpret_cast<const float4*>(time_b);

    float4 acc[15];
#pragma unroll
    for (int j = 0; j < 15; ++j) acc[j] = (float4){0.f, 0.f, 0.f, 0.f};

    int4 en_n = (c > 0) ? entries[o0] : make_int4(0, 0, 0, 0);
    for (int i = 0; i < c; ++i) {
        int4 en = en_n;
        if (i + 1 < c) en_n = entries[o0 + i + 1];  // prefetch next entry
        const float4* mo = reinterpret_cast<const float4*>(memory + (size_t)en.x * MD);
        const float4* rw = reinterpret_cast<const float4*>(raw_msg + (size_t)en.y * MSGD);
        float trel = __int_as_float(en.z);
#pragma unroll
        for (int j = 0; j < 15; ++j) {
            int u = tsub + 8 * j;
            if (u >= 25 && u < 118) {
                int q = u - 25;
                float4 v;
                if (q < 25) {
                    v = mo[q];
                } else if (q < 68) {
                    v = rw[q - 25];
                } else {
                    float4 w = tw4[q - 68], b = tb4[q - 68];
                    v.x = cosf(trel * w.x + b.x);
                    v.y = cosf(trel * w.y + b.y);
                    v.z = cosf(trel * w.z + b.z);
                    v.w = cosf(trel * w.w + b.w);
                }
                acc[j].x += v.x; acc[j].y += v.y; acc[j].z += v.z; acc[j].w += v.w;
            }
        }
    }

    float ci = 1.0f / fmaxf((float)c, 1.0f);
    char* tile = reinterpret_cast<char*>(agg) + (size_t)(node >> 6) * TILE_BYTES;
    int local = node & 63;
    int rbase = local * 960;
    int swz = (local & 7) << 4;
    const float4* ms = reinterpret_cast<const float4*>(memory + (size_t)node * MD);

#pragma unroll
    for (int j = 0; j < 15; ++j) {
        int u = tsub + 8 * j;
        float4 v;
        if (u < 25) {
            v = ms[u];
        } else if (u < 118) {
            v = acc[j];
            v.x *= ci; v.y *= ci; v.z *= ci; v.w *= ci;
        } else {
            v = (float4){0.f, 0.f, 0.f, 0.f};
        }
        ushort4 h;
        h.x = f2bf(v.x); h.y = f2bf(v.y); h.z = f2bf(v.z); h.w = f2bf(v.w);
        *reinterpret_cast<ushort4*>(tile + ((rbase + 8 * u) ^ swz)) = h;
    }
}

// ---------------- K_gemm: fused single-pass bf16 MFMA GRU ----------------
// 8 waves; each wave: full 64-node M (4 m-frags) x private 3-4 n-frags.
__global__ __launch_bounds__(512, 4) void tgn_gemm(
    const float* __restrict__ memory, const unsigned short* __restrict__ agg,
    const unsigned short* __restrict__ Bp,
    const float* __restrict__ b_ih, const float* __restrict__ b_hh,
    const int* __restrict__ cnt, float* __restrict__ out)
{
    __shared__ __align__(16) unsigned short lds[64 * 480];  // A tile; reused as Gl[400][72]
    __shared__ float cnt_s[NB];
    int tid = threadIdx.x;
    int n0 = blockIdx.x * NB;

    if (tid < NB) cnt_s[tid] = (float)cnt[n0 + tid];

    // stage A tile: 60 KB linear DMA (layout already swizzled in global)
    {
        int lane = tid & 63;
        int wv0 = tid >> 6;
        const char* gsrc = reinterpret_cast<const char*>(agg) + (size_t)blockIdx.x * TILE_BYTES;
        char* lbase = reinterpret_cast<char*>(lds);
        for (int i = wv0; i < 60; i += 8) {
            gload_lds16(gsrc + i * 1024 + lane * 16, lbase + i * 1024);
        }
    }
    __syncthreads();

    int lane = tid & 63;
    int wv = tid >> 6;
    int l15 = lane & 15;
    int kg8 = (lane >> 4) << 3;
    int f0 = (wv == 0) ? 0 : (4 + 3 * (wv - 1));  // n-frag start: {0,4,7,...,22}
    int cw = (wv == 0) ? 4 : 3;                    // n-frags this wave

    f32x4 acc[4][4];
#pragma unroll
    for (int g = 0; g < 4; ++g)
#pragma unroll
        for (int i = 0; i < 4; ++i) acc[g][i] = (f32x4){0.f, 0.f, 0.f, 0.f};

    const bf16x8* BpB = reinterpret_cast<const bf16x8*>(Bp);
    const char* ldsc = reinterpret_cast<const char*>(lds);

    for (int ks = 0; ks < KS; ++ks) {
        int k0 = ks * 32 + kg8;
        const bf16x8* bp = BpB + ((size_t)(ks * NFRAG + f0)) * 64 + lane;
        bf16x8 b[4];
#pragma unroll
        for (int i = 0; i < 4; ++i)
            if (i < cw) b[i] = bp[i * 64];
#pragma unroll
        for (int g = 0; g < 4; ++g) {
            int r = g * 16 + l15;
            int ab = (r * 960 + 2 * k0) ^ ((r & 7) << 4);
            bf16x8 a = *reinterpret_cast<const bf16x8*>(ldsc + ab);
#pragma unroll
            for (int i = 0; i < 4; ++i)
                if (i < cw)
                    acc[g][i] = __builtin_amdgcn_mfma_f32_16x16x32_bf16(a, b[i], acc[g][i], 0, 0, 0);
        }
    }

    __syncthreads();  // all waves done reading A; reuse LDS as Gl[400][72] bf16

    unsigned short* Gl = lds;
    int kq = (lane >> 4) << 2;
#pragma unroll
    for (int i = 0; i < 4; ++i) {
        if (i < cw) {
            int col = (f0 + i) * 16 + l15;
            float bias = (col < 200) ? (b_ih[col] + b_hh[col])
                       : (col < 300) ? b_ih[col] : b_hh[col - 100];
#pragma unroll
            for (int g = 0; g < 4; ++g) {
                int node = g * 16 + kq;
#pragma unroll
                for (int rp = 0; rp < 2; ++rp) {
                    unsigned int lo = f2bf(acc[g][i][2 * rp] + bias);
                    unsigned int hi = f2bf(acc[g][i][2 * rp + 1] + bias);
                    *reinterpret_cast<unsigned int*>(&Gl[col * GLS + node + 2 * rp]) =
                        lo | (hi << 16);
                }
            }
        }
    }
    __syncthreads();

    // final elementwise GRU
    for (int idx = tid; idx < NB * MD; idx += 512) {
        int n = idx / MD, j = idx - n * MD;
        float rp = bf2f(Gl[j * GLS + n]);
        float zp = bf2f(Gl[(100 + j) * GLS + n]);
        float inp = bf2f(Gl[(200 + j) * GLS + n]);
        float hnp = bf2f(Gl[(300 + j) * GLS + n]);
        float r = sigmoidf_(rp);
        float z = sigmoidf_(zp);
        float nn = tanhf(inp + r * hnp);
        float mv = memory[(size_t)(n0 + n) * MD + j];
        float h = (1.0f - z) * nn + z * mv;
        out[(size_t)(n0 + n) * MD + j] = (cnt_s[n] > 0.0f) ? h : mv;
    }
}

extern "C" void kernel_launch(void* const* d_in, const int* in_sizes, int n_in,
                              void* d_out, int out_size, void* d_ws, size_t ws_size,
                              hipStream_t stream)
{
    const float* memory      = (const float*)d_in[0];
    const float* raw_msg     = (const float*)d_in[1];
    const float* time_w      = (const float*)d_in[2];
    const float* time_b      = (const float*)d_in[3];
    const float* w_ih        = (const float*)d_in[4];
    const float* w_hh        = (const float*)d_in[5];
    const float* b_ih        = (const float*)d_in[6];
    const float* b_hh        = (const float*)d_in[7];
    const int*   last_update = (const int*)d_in[8];
    const int*   src         = (const int*)d_in[9];
    const int*   dst         = (const int*)d_in[10];
    const int*   tarr        = (const int*)d_in[11];
    float* out = (float*)d_out;

    // ws layout: cnt[N] off[N] cur[N] psum[256] | entries int4[2E] | agg bf16 | Bp
    int* cnt  = (int*)d_ws;
    int* off  = cnt + NND;
    int* cur  = off + NND;
    int* psum = cur + NND;
    int4* entries = (int4*)(psum + 256);
    unsigned short* agg = (unsigned short*)(entries + 2 * NEV);
    const int NTILE = NND / NB;  // 3125
    unsigned short* Bp = agg + (size_t)NTILE * (TILE_BYTES / 2);
    size_t need = (size_t)((char*)(Bp + BP_ELEMS) - (char*)d_ws);
    if (ws_size < need) return;

    const int NBLK = (NND + 1023) / 1024;  // 196

    hipMemsetAsync(cnt, 0, NND * sizeof(int), stream);
    tgn_prep<<<(BP_ELEMS + 255) / 256, 256, 0, stream>>>(w_ih, w_hh, Bp);
    k_count<<<(NEV + 255) / 256, 256, 0, stream>>>(src, dst, cnt);
    k_scan1<<<NBLK, 256, 0, stream>>>(cnt, off, psum);
    k_scan2<<<1, 256, 0, stream>>>(psum, NBLK);
    k_scan3<<<NBLK, 256, 0, stream>>>(off, psum, cur);
    k_place<<<(NEV + 255) / 256, 256, 0, stream>>>(src, dst, tarr, last_update, cur, entries);
    k_aggr<<<(NND + 31) / 32, 256, 0, stream>>>(memory, raw_msg, time_w, time_b,
                                                cnt, off, entries, agg);
    tgn_gemm<<<NTILE, 512, 0, stream>>>(memory, agg, Bp, b_ih, b_hh, cnt, out);
}